// Round 4
// baseline (137.673 us; speedup 1.0000x reference)
//
#include <hip/hip_runtime.h>

#define NGRID 1024
#define EPS_DX 1e-10f

typedef float f32x4 __attribute__((ext_vector_type(4)));
typedef float f32x2 __attribute__((ext_vector_type(2)));

// ---------------------------------------------------------------------------
// Kernel A: build the two adaptive grids (1024 floats each) into d_ws.
// ---------------------------------------------------------------------------
__global__ __launch_bounds__(1024) void build_grids(
    const float* __restrict__ incr_x,
    const float* __restrict__ incr_y,
    float* __restrict__ gx,
    float* __restrict__ gy)
{
    const float* incr = (blockIdx.x == 0) ? incr_x : incr_y;
    float* g = (blockIdx.x == 0) ? gx : gy;

    const int m = NGRID - 1;   // 1023 increments
    __shared__ double s[NGRID];

    int t = threadIdx.x;
    double v = 0.0;
    if (t < m) {
        double x = (double)incr[t];
        double sp = log1p(exp(x));          // softplus
        v = fmax(sp, 1e-6);
    }
    s[t] = v;
    __syncthreads();

    #pragma unroll
    for (int off = 1; off < NGRID; off <<= 1) {
        double add = (t >= off) ? s[t - off] : 0.0;
        __syncthreads();
        s[t] += add;
        __syncthreads();
    }

    double total = s[m - 1];
    if (t < m - 1) g[t + 1] = (float)(s[t] / total);
    if (t == 0) {
        g[0] = 0.0f;
        g[NGRID - 1] = 1.0f;
    }
}

// ---------------------------------------------------------------------------
// Kernel A2: build cell table U4[i][j] = (u00,u01,u10,u11), i,j in [0,1022].
// Row stride 1024 so indexing is a shift. One float4 gather per point later.
// ---------------------------------------------------------------------------
__global__ __launch_bounds__(256) void build_cells(
    const float* __restrict__ u, f32x4* __restrict__ U4)
{
    int t = blockIdx.x * 256 + threadIdx.x;
    if (t >= (NGRID - 1) * NGRID) return;
    int i = t >> 10;
    int j = t & (NGRID - 1);
    if (j > NGRID - 2) return;
    const float* up = u + (i << 10) + j;
    f32x4 c;
    c.x = up[0];          // u00
    c.y = up[1];          // u01
    c.z = up[NGRID];      // u10
    c.w = up[NGRID + 1];  // u11
    U4[(i << 10) + j] = c;
}

// ---------------------------------------------------------------------------
// Branchless cell lookup: predict j = floor(x*1023), correct by at most one
// step (grid deviates <0.1 cells from uniform).
// Exactly reproduces clip(searchsorted(g,x,'left')-1, 0, 1022).  (validated R1/R2)
// ---------------------------------------------------------------------------
__device__ __forceinline__ int find_cell(float x, const float2* __restrict__ PG,
                                         float& gl, float& gr)
{
    int j = (int)(x * 1023.0f);
    j = min(max(j, 0), NGRID - 2);
    float2 p = PG[j];
    int d = (p.y < x) ? 1 : ((j > 0 && p.x >= x) ? -1 : 0);
    j += d;
    float2 q = PG[j];
    gl = q.x; gr = q.y;
    return j;
}

// ---------------------------------------------------------------------------
// Kernel B: 8 points per thread, one float4 cell-gather per point.
// Streaming I/O fully coalesced: thread f loads xy float4s {f+k*S}, k=0..3,
// writes out f32x2s {f+k*S}. S = nt (= total threads).
// ---------------------------------------------------------------------------
__global__ __launch_bounds__(512) void interp_kernel8(
    const f32x4* __restrict__ xy,
    const f32x4* __restrict__ U4,
    const float* __restrict__ gx,
    const float* __restrict__ gy,
    f32x2* __restrict__ out2,
    int nt)                          // threads total; also the k-stride S
{
    __shared__ float2 PGX[NGRID];    // PG[j] = (g[j], g[j+1])
    __shared__ float2 PGY[NGRID];
    for (int i = threadIdx.x; i < NGRID - 1; i += blockDim.x) {
        PGX[i] = make_float2(gx[i], gx[i + 1]);
        PGY[i] = make_float2(gy[i], gy[i + 1]);
    }
    __syncthreads();

    int f = blockIdx.x * blockDim.x + threadIdx.x;
    if (f >= nt) return;

    f32x4 p[4];
    #pragma unroll
    for (int k = 0; k < 4; ++k)
        p[k] = __builtin_nontemporal_load(&xy[f + k * nt]);

    // per point: cell weights (n1x, n1y) and table index
    float n1x[8], n1y[8];
    int idx[8];
    #pragma unroll
    for (int k = 0; k < 4; ++k) {
        float xa = p[k].x, ya = p[k].y;
        float xb = p[k].z, yb = p[k].w;
        float xl, xr, yl, yr;
        int jx, jy;

        jx = find_cell(xa, PGX, xl, xr);
        jy = find_cell(ya, PGY, yl, yr);
        idx[2 * k] = (jx << 10) + jy;
        n1x[2 * k] = (xr - xa) / fmaxf(xr - xl, EPS_DX);
        n1y[2 * k] = (yr - ya) / fmaxf(yr - yl, EPS_DX);

        jx = find_cell(xb, PGX, xl, xr);
        jy = find_cell(yb, PGY, yl, yr);
        idx[2 * k + 1] = (jx << 10) + jy;
        n1x[2 * k + 1] = (xr - xb) / fmaxf(xr - xl, EPS_DX);
        n1y[2 * k + 1] = (yr - yb) / fmaxf(yr - yl, EPS_DX);
    }

    // issue all 8 cell gathers before any use
    f32x4 c[8];
    #pragma unroll
    for (int k = 0; k < 8; ++k)
        c[k] = U4[idx[k]];

    #pragma unroll
    for (int k = 0; k < 4; ++k) {
        f32x2 r;
        {
            float ax = n1x[2 * k], ay = n1y[2 * k];
            float bx = 1.0f - ax,  by = 1.0f - ay;
            r.x = ax * (ay * c[2 * k].x + by * c[2 * k].y)
                + bx * (ay * c[2 * k].z + by * c[2 * k].w);
        }
        {
            float ax = n1x[2 * k + 1], ay = n1y[2 * k + 1];
            float bx = 1.0f - ax,      by = 1.0f - ay;
            r.y = ax * (ay * c[2 * k + 1].x + by * c[2 * k + 1].y)
                + bx * (ay * c[2 * k + 1].z + by * c[2 * k + 1].w);
        }
        __builtin_nontemporal_store(r, &out2[f + k * nt]);
    }
}

// ---------------------------------------------------------------------------
// Fallback (ws too small for U4): R2-style 4-pt kernel gathering u directly.
// ---------------------------------------------------------------------------
__global__ __launch_bounds__(512) void interp_kernel4(
    const f32x4* __restrict__ xy,
    const float* __restrict__ u,
    const float* __restrict__ gx,
    const float* __restrict__ gy,
    f32x4* __restrict__ out,
    int nf)
{
    __shared__ float2 PGX[NGRID];
    __shared__ float2 PGY[NGRID];
    for (int i = threadIdx.x; i < NGRID - 1; i += blockDim.x) {
        PGX[i] = make_float2(gx[i], gx[i + 1]);
        PGY[i] = make_float2(gy[i], gy[i + 1]);
    }
    __syncthreads();

    int f = blockIdx.x * blockDim.x + threadIdx.x;
    if (f >= nf) return;

    f32x4 a = __builtin_nontemporal_load(&xy[2 * f]);
    f32x4 b = __builtin_nontemporal_load(&xy[2 * f + 1]);
    float xs[4] = {a.x, a.z, b.x, b.z};
    float ys[4] = {a.y, a.w, b.y, b.w};

    int jx[4], jy[4];
    float xl[4], xr[4], yl[4], yr[4];
    #pragma unroll
    for (int k = 0; k < 4; ++k) {
        jx[k] = find_cell(xs[k], PGX, xl[k], xr[k]);
        jy[k] = find_cell(ys[k], PGY, yl[k], yr[k]);
    }
    float u00[4], u10[4], u01[4], u11[4];
    #pragma unroll
    for (int k = 0; k < 4; ++k) {
        const float* up = u + jx[k] * NGRID + jy[k];
        u00[k] = up[0];
        u01[k] = up[1];
        u10[k] = up[NGRID];
        u11[k] = up[NGRID + 1];
    }
    f32x4 r;
    #pragma unroll
    for (int k = 0; k < 4; ++k) {
        float dx = fmaxf(xr[k] - xl[k], EPS_DX);
        float dy = fmaxf(yr[k] - yl[k], EPS_DX);
        float n1xv = (xr[k] - xs[k]) / dx;
        float n2xv = (xs[k] - xl[k]) / dx;
        float n1yv = (yr[k] - ys[k]) / dy;
        float n2yv = (ys[k] - yl[k]) / dy;
        r[k] = n1xv * n1yv * u00[k] + n2xv * n1yv * u10[k]
             + n1xv * n2yv * u01[k] + n2xv * n2yv * u11[k];
    }
    __builtin_nontemporal_store(r, &out[f]);
}

// ---------------------------------------------------------------------------
extern "C" void kernel_launch(void* const* d_in, const int* in_sizes, int n_in,
                              void* d_out, int out_size, void* d_ws, size_t ws_size,
                              hipStream_t stream)
{
    const float* x_eval = (const float*)d_in[0];   // (8M, 2) f32
    const float* incr_x = (const float*)d_in[1];   // (1023,) f32
    const float* incr_y = (const float*)d_in[2];   // (1023,) f32
    const float* u      = (const float*)d_in[3];   // (1024,1024) f32
    float* out = (float*)d_out;

    float* gx = (float*)d_ws;                      // 1024 f32
    float* gy = gx + NGRID;                        // 1024 f32
    f32x4* U4 = (f32x4*)((char*)d_ws + 8192);      // (1023)x(1024) float4, 16.75 MB

    size_t need = 8192 + (size_t)(NGRID - 1) * NGRID * sizeof(f32x4);

    build_grids<<<2, NGRID, 0, stream>>>(incr_x, incr_y, gx, gy);

    if (ws_size >= need) {
        int nc = (NGRID - 1) * NGRID;
        build_cells<<<(nc + 255) / 256, 256, 0, stream>>>(u, U4);

        int nt = out_size / 8;                     // 1,000,000 threads; also stride S
        int blocks = (nt + 511) / 512;
        interp_kernel8<<<blocks, 512, 0, stream>>>(
            (const f32x4*)x_eval, U4, gx, gy, (f32x2*)out, nt);
    } else {
        int nf = out_size / 4;
        int blocks = (nf + 511) / 512;
        interp_kernel4<<<blocks, 512, 0, stream>>>(
            (const f32x4*)x_eval, u, gx, gy, (f32x4*)out, nf);
    }
}

// Round 5
// 103.231 us; speedup vs baseline: 1.3336x; 1.3336x over previous
//
#include <hip/hip_runtime.h>

#define NGRID 1024
#define EPS_DX 1e-10f

typedef float f32x4 __attribute__((ext_vector_type(4)));
typedef float f32x2 __attribute__((ext_vector_type(2)));

// ---------------------------------------------------------------------------
// Kernel A: build the two adaptive grids (1024 floats each) into d_ws.
// ---------------------------------------------------------------------------
__global__ __launch_bounds__(1024) void build_grids(
    const float* __restrict__ incr_x,
    const float* __restrict__ incr_y,
    float* __restrict__ gx,
    float* __restrict__ gy)
{
    const float* incr = (blockIdx.x == 0) ? incr_x : incr_y;
    float* g = (blockIdx.x == 0) ? gx : gy;

    const int m = NGRID - 1;   // 1023 increments
    __shared__ double s[NGRID];

    int t = threadIdx.x;
    double v = 0.0;
    if (t < m) {
        double x = (double)incr[t];
        double sp = log1p(exp(x));          // softplus
        v = fmax(sp, 1e-6);
    }
    s[t] = v;
    __syncthreads();

    #pragma unroll
    for (int off = 1; off < NGRID; off <<= 1) {
        double add = (t >= off) ? s[t - off] : 0.0;
        __syncthreads();
        s[t] += add;
        __syncthreads();
    }

    double total = s[m - 1];
    if (t < m - 1) g[t + 1] = (float)(s[t] / total);
    if (t == 0) {
        g[0] = 0.0f;
        g[NGRID - 1] = 1.0f;
    }
}

// ---------------------------------------------------------------------------
// Kernel A2: pack horizontal pairs (u[i][j], u[i][j+1]) as 2xbf16 in 4 bytes.
// Table is 1024x1024x4B = 4 MB -> L2-resident. RNE rounding.
// ---------------------------------------------------------------------------
__device__ __forceinline__ unsigned int bf16_rne(float x)
{
    unsigned int v = __float_as_uint(x);
    return (v + 0x7FFFu + ((v >> 16) & 1u)) >> 16;
}

__global__ __launch_bounds__(256) void build_pairs(
    const float* __restrict__ u, unsigned int* __restrict__ UH)
{
    int t = blockIdx.x * 256 + threadIdx.x;
    if (t >= NGRID * NGRID) return;
    int j = t & (NGRID - 1);
    float a = u[t];
    float b = (j < NGRID - 1) ? u[t + 1] : 0.0f;   // j=1023 never read
    UH[t] = bf16_rne(a) | (bf16_rne(b) << 16);
}

// ---------------------------------------------------------------------------
// Branchless cell lookup: predict j = floor(x*1023), correct by at most one
// step. Exactly reproduces clip(searchsorted(g,x,'left')-1, 0, 1022).
// (validated R1/R2/R4)
// ---------------------------------------------------------------------------
__device__ __forceinline__ int find_cell(float x, const float2* __restrict__ PG,
                                         float& gl, float& gr)
{
    int j = (int)(x * 1023.0f);
    j = min(max(j, 0), NGRID - 2);
    float2 p = PG[j];
    int d = (p.y < x) ? 1 : ((j > 0 && p.x >= x) ? -1 : 0);
    j += d;
    float2 q = PG[j];
    gl = q.x; gr = q.y;
    return j;
}

// ---------------------------------------------------------------------------
// Kernel B: 8 points per thread, TWO 4-byte gathers per point (rows jx, jx+1),
// both from the 4 MB L2-resident bf16-pair table.
// Streaming I/O fully coalesced: thread f handles xy float4s {f+k*S}, k=0..3.
// ---------------------------------------------------------------------------
__global__ __launch_bounds__(512) void interp_kernel8(
    const f32x4* __restrict__ xy,
    const unsigned int* __restrict__ UH,
    const float* __restrict__ gx,
    const float* __restrict__ gy,
    f32x2* __restrict__ out2,
    int nt)                          // threads total; also the k-stride S
{
    __shared__ float2 PGX[NGRID];    // PG[j] = (g[j], g[j+1])
    __shared__ float2 PGY[NGRID];
    for (int i = threadIdx.x; i < NGRID - 1; i += blockDim.x) {
        PGX[i] = make_float2(gx[i], gx[i + 1]);
        PGY[i] = make_float2(gy[i], gy[i + 1]);
    }
    __syncthreads();

    int f = blockIdx.x * blockDim.x + threadIdx.x;
    if (f >= nt) return;

    f32x4 p[4];
    #pragma unroll
    for (int k = 0; k < 4; ++k)
        p[k] = __builtin_nontemporal_load(&xy[f + k * nt]);

    // per point: weights and table index
    float n1x[8], n1y[8];
    int idx[8];
    #pragma unroll
    for (int k = 0; k < 4; ++k) {
        float xa = p[k].x, ya = p[k].y;
        float xb = p[k].z, yb = p[k].w;
        float xl, xr, yl, yr;
        int jx, jy;

        jx = find_cell(xa, PGX, xl, xr);
        jy = find_cell(ya, PGY, yl, yr);
        idx[2 * k] = (jx << 10) + jy;
        n1x[2 * k] = (xr - xa) / fmaxf(xr - xl, EPS_DX);
        n1y[2 * k] = (yr - ya) / fmaxf(yr - yl, EPS_DX);

        jx = find_cell(xb, PGX, xl, xr);
        jy = find_cell(yb, PGY, yl, yr);
        idx[2 * k + 1] = (jx << 10) + jy;
        n1x[2 * k + 1] = (xr - xb) / fmaxf(xr - xl, EPS_DX);
        n1y[2 * k + 1] = (yr - yb) / fmaxf(yr - yl, EPS_DX);
    }

    // issue all 16 gathers before any use
    unsigned int va[8], vb[8];
    #pragma unroll
    for (int k = 0; k < 8; ++k) {
        va[k] = UH[idx[k]];            // (u00, u01)
        vb[k] = UH[idx[k] + NGRID];    // (u10, u11)
    }

    #pragma unroll
    for (int k = 0; k < 4; ++k) {
        f32x2 r;
        #pragma unroll
        for (int h = 0; h < 2; ++h) {
            int q = 2 * k + h;
            float u00 = __uint_as_float(va[q] << 16);
            float u01 = __uint_as_float(va[q] & 0xFFFF0000u);
            float u10 = __uint_as_float(vb[q] << 16);
            float u11 = __uint_as_float(vb[q] & 0xFFFF0000u);
            float ax = n1x[q], ay = n1y[q];
            float bx = 1.0f - ax, by = 1.0f - ay;
            float val = ax * (ay * u00 + by * u01)
                      + bx * (ay * u10 + by * u11);
            if (h == 0) r.x = val; else r.y = val;
        }
        __builtin_nontemporal_store(r, &out2[f + k * nt]);
    }
}

// ---------------------------------------------------------------------------
// Fallback (ws too small): R2-style 4-pt kernel gathering u directly.
// ---------------------------------------------------------------------------
__global__ __launch_bounds__(512) void interp_kernel4(
    const f32x4* __restrict__ xy,
    const float* __restrict__ u,
    const float* __restrict__ gx,
    const float* __restrict__ gy,
    f32x4* __restrict__ out,
    int nf)
{
    __shared__ float2 PGX[NGRID];
    __shared__ float2 PGY[NGRID];
    for (int i = threadIdx.x; i < NGRID - 1; i += blockDim.x) {
        PGX[i] = make_float2(gx[i], gx[i + 1]);
        PGY[i] = make_float2(gy[i], gy[i + 1]);
    }
    __syncthreads();

    int f = blockIdx.x * blockDim.x + threadIdx.x;
    if (f >= nf) return;

    f32x4 a = __builtin_nontemporal_load(&xy[2 * f]);
    f32x4 b = __builtin_nontemporal_load(&xy[2 * f + 1]);
    float xs[4] = {a.x, a.z, b.x, b.z};
    float ys[4] = {a.y, a.w, b.y, b.w};

    int jx[4], jy[4];
    float xl[4], xr[4], yl[4], yr[4];
    #pragma unroll
    for (int k = 0; k < 4; ++k) {
        jx[k] = find_cell(xs[k], PGX, xl[k], xr[k]);
        jy[k] = find_cell(ys[k], PGY, yl[k], yr[k]);
    }
    float u00[4], u10[4], u01[4], u11[4];
    #pragma unroll
    for (int k = 0; k < 4; ++k) {
        const float* up = u + jx[k] * NGRID + jy[k];
        u00[k] = up[0];
        u01[k] = up[1];
        u10[k] = up[NGRID];
        u11[k] = up[NGRID + 1];
    }
    f32x4 r;
    #pragma unroll
    for (int k = 0; k < 4; ++k) {
        float dx = fmaxf(xr[k] - xl[k], EPS_DX);
        float dy = fmaxf(yr[k] - yl[k], EPS_DX);
        float n1xv = (xr[k] - xs[k]) / dx;
        float n2xv = (xs[k] - xl[k]) / dx;
        float n1yv = (yr[k] - ys[k]) / dy;
        float n2yv = (ys[k] - yl[k]) / dy;
        r[k] = n1xv * n1yv * u00[k] + n2xv * n1yv * u10[k]
             + n1xv * n2yv * u01[k] + n2xv * n2yv * u11[k];
    }
    __builtin_nontemporal_store(r, &out[f]);
}

// ---------------------------------------------------------------------------
extern "C" void kernel_launch(void* const* d_in, const int* in_sizes, int n_in,
                              void* d_out, int out_size, void* d_ws, size_t ws_size,
                              hipStream_t stream)
{
    const float* x_eval = (const float*)d_in[0];   // (8M, 2) f32
    const float* incr_x = (const float*)d_in[1];   // (1023,) f32
    const float* incr_y = (const float*)d_in[2];   // (1023,) f32
    const float* u      = (const float*)d_in[3];   // (1024,1024) f32
    float* out = (float*)d_out;

    float* gx = (float*)d_ws;                          // 1024 f32
    float* gy = gx + NGRID;                            // 1024 f32
    unsigned int* UH = (unsigned int*)((char*)d_ws + 8192);  // 4 MB bf16-pair table

    size_t need = 8192 + (size_t)NGRID * NGRID * sizeof(unsigned int);

    build_grids<<<2, NGRID, 0, stream>>>(incr_x, incr_y, gx, gy);

    if (ws_size >= need) {
        int nc = NGRID * NGRID;
        build_pairs<<<(nc + 255) / 256, 256, 0, stream>>>(u, UH);

        int nt = out_size / 8;                     // 1,000,000 threads; stride S
        int blocks = (nt + 511) / 512;
        interp_kernel8<<<blocks, 512, 0, stream>>>(
            (const f32x4*)x_eval, UH, gx, gy, (f32x2*)out, nt);
    } else {
        int nf = out_size / 4;
        int blocks = (nf + 511) / 512;
        interp_kernel4<<<blocks, 512, 0, stream>>>(
            (const f32x4*)x_eval, u, gx, gy, (f32x4*)out, nf);
    }
}